// Round 13
// baseline (344.308 us; speedup 1.0000x reference)
//
#include <hip/hip_runtime.h>
#include <hip/hip_bf16.h>
#include <math.h>

// B=4, S=2048, D=1024, H=16, DK=64. fp32 I/O. bf16 MFMA internals.

#define B_SZ   4
#define S_LEN  2048
#define D_DIM  1024
#define NH     16
#define DKD    64
#define M_TOT  (B_SZ * S_LEN)   // 8192

typedef __bf16 bf16_t;
typedef bf16_t bf16x8 __attribute__((ext_vector_type(8)));
typedef bf16_t bf16x4 __attribute__((ext_vector_type(4)));
typedef float  f32x4  __attribute__((ext_vector_type(4)));

typedef __attribute__((address_space(1))) void gvoid;
typedef __attribute__((address_space(3))) void lvoid;

extern "C" __device__ float __ocml_native_exp2_f32(float);  // single v_exp_f32

// ---------------------------------------------------------------------------
// fp32 -> bf16 convert. cvt3: three weight matrices in one launch (z selects).
// ---------------------------------------------------------------------------
__global__ __launch_bounds__(256)
void cvt3_kernel(const float* __restrict__ s0, const float* __restrict__ s1,
                 const float* __restrict__ s2, bf16_t* __restrict__ d0,
                 bf16_t* __restrict__ d1, bf16_t* __restrict__ d2, int n4)
{
    const float* src = (blockIdx.z == 0) ? s0 : (blockIdx.z == 1) ? s1 : s2;
    bf16_t*      dst = (blockIdx.z == 0) ? d0 : (blockIdx.z == 1) ? d1 : d2;
    const int i = blockIdx.x * blockDim.x + threadIdx.x;
    if (i < n4) {
        f32x4 v = *(const f32x4*)(src + (size_t)i * 4);
        bf16x4 o;
        #pragma unroll
        for (int j = 0; j < 4; ++j) o[j] = (bf16_t)v[j];
        *(bf16x4*)(dst + (size_t)i * 4) = o;
    }
}

__global__ __launch_bounds__(256)
void cvt_kernel(const float* __restrict__ src, bf16_t* __restrict__ dst, int n4)
{
    const int i = blockIdx.x * blockDim.x + threadIdx.x;
    if (i < n4) {
        f32x4 v = *(const f32x4*)(src + (size_t)i * 4);
        bf16x4 o;
        #pragma unroll
        for (int j = 0; j < 4; ++j) o[j] = (bf16_t)v[j];
        *(bf16x4*)(dst + (size_t)i * 4) = o;
    }
}

// ---------------------------------------------------------------------------
// Fused QKV projection GEMM, grid (64, 8, 3). r5-measured-best body (107.5us):
// BM=BN=128, B double-buffered gload_lds with counted vmcnt, A reg-staged.
// ---------------------------------------------------------------------------
__global__ __launch_bounds__(256, 3)
void qkv_gemm(const float* __restrict__ Aq, const float* __restrict__ Ak,
              const float* __restrict__ Av,
              const bf16_t* __restrict__ Wqb, const bf16_t* __restrict__ Wkb,
              const bf16_t* __restrict__ Wvb,
              const float* __restrict__ bq, const float* __restrict__ bk,
              const float* __restrict__ bv,
              bf16_t* __restrict__ Qw, bf16_t* __restrict__ Kw,
              bf16_t* __restrict__ Vt, float qscale)
{
    constexpr int K = 1024, N = 1024;
    constexpr int BM = 128, BK = 64;
    constexpr int NT = K / BK;     // 16 K-steps

    __shared__ __align__(16) bf16_t lA[2][BM * 32];      // [sub]      16 KB
    __shared__ __align__(16) bf16_t lB[2][2][128 * 32];  // [buf][sub] 32 KB

    const int z = blockIdx.z;
    const float* A  = (z == 0) ? Aq : (z == 1) ? Ak : Av;
    const bf16_t* W = (z == 0) ? Wqb : (z == 1) ? Wkb : Wvb;
    const float* bias = (z == 0) ? bq : (z == 1) ? bk : bv;
    const float scale = (z == 0) ? qscale : 1.0f;

    const int tid  = threadIdx.x;
    const int wave = tid >> 6;
    const int lane = tid & 63;

    const int row0 = blockIdx.x * BM;
    const int col0 = blockIdx.y * 128;

    const int wr = (wave >> 1) * 64;
    const int wc = (wave & 1) * 64;

    f32x4 acc[4][4] = {};

    const int frow = lane & 15;
    const int kq   = (lane >> 4) * 8;

    const int arow = tid >> 3;          // + p*32
    const int ak8  = (tid & 7) * 8;     // k offset in tile
    const int asub = (tid >> 2) & 1;
    const int akk  = (tid & 3) * 8;

    auto stageB = [&](int k0s, int bufi) {
        #pragma unroll
        for (int s = 0; s < 2; ++s)
            #pragma unroll
            for (int c2 = 0; c2 < 2; ++c2) {
                const int chunk = c2 * 4 + wave;
                const int e     = chunk * 512 + lane * 8;
                const int rr    = e >> 5;
                const int kk    = e & 31;
                __builtin_amdgcn_global_load_lds(
                    (gvoid*)(W + (size_t)(col0 + rr) * K + k0s + 32 * s + kk),
                    (lvoid*)(&lB[bufi][s][chunk * 512]), 16, 0, 0);
            }
    };

    stageB(0, 0);

    f32x4 pa[4][2];
    #pragma unroll
    for (int p = 0; p < 4; ++p) {
        const float* g = A + (size_t)(row0 + p * 32 + arow) * K + ak8;
        pa[p][0] = *(const f32x4*)g;
        pa[p][1] = *(const f32x4*)(g + 4);
    }

    for (int t = 0; t < NT; ++t) {
        const int k0  = t * BK;
        const int buf = t & 1;

        if (t + 1 < NT) stageB(k0 + BK, buf ^ 1);

        #pragma unroll
        for (int p = 0; p < 4; ++p) {
            bf16x8 a8;
            #pragma unroll
            for (int j = 0; j < 4; ++j) {
                a8[j]     = (bf16_t)pa[p][0][j];
                a8[4 + j] = (bf16_t)pa[p][1][j];
            }
            *(bf16x8*)(&lA[asub][(p * 32 + arow) * 32 + akk]) = a8;
        }

        if (t + 1 < NT)
            asm volatile("s_waitcnt vmcnt(4) lgkmcnt(0)" ::: "memory");
        else
            asm volatile("s_waitcnt vmcnt(0) lgkmcnt(0)" ::: "memory");
        __builtin_amdgcn_s_barrier();

        if (t + 1 < NT) {
            #pragma unroll
            for (int p = 0; p < 4; ++p) {
                const float* g = A + (size_t)(row0 + p * 32 + arow) * K + (k0 + BK) + ak8;
                pa[p][0] = *(const f32x4*)g;
                pa[p][1] = *(const f32x4*)(g + 4);
            }
        }

        #pragma unroll
        for (int s = 0; s < 2; ++s) {
            bf16x8 af[4], bfr[4];
            #pragma unroll
            for (int i = 0; i < 4; ++i) {
                af[i]  = *(const bf16x8*)(&lA[s][(wr + i * 16 + frow) * 32 + kq]);
                bfr[i] = *(const bf16x8*)(&lB[buf][s][(wc + i * 16 + frow) * 32 + kq]);
            }
            #pragma unroll
            for (int i = 0; i < 4; ++i)
                #pragma unroll
                for (int j = 0; j < 4; ++j)
                    acc[i][j] = __builtin_amdgcn_mfma_f32_16x16x32_bf16(af[i], bfr[j], acc[i][j], 0, 0, 0);
        }

        asm volatile("" ::: "memory");
        __builtin_amdgcn_s_barrier();
    }

    // C/D layout: col=lane&15, row=(lane>>4)*4+reg  [m89/m91-verified]
    const int rb   = (lane >> 4) * 4;
    const int ccol = lane & 15;
    #pragma unroll
    for (int j = 0; j < 4; ++j) {
        const int n = col0 + wc + j * 16 + ccol;
        const float bvv = bias[n];
        #pragma unroll
        for (int i = 0; i < 4; ++i) {
            const int m = row0 + wr + i * 16 + rb;
            if (z == 2) {
                bf16x4 o4;
                #pragma unroll
                for (int r = 0; r < 4; ++r) o4[r] = (bf16_t)(acc[i][j][r] + bvv);
                *(bf16x4*)(Vt + (size_t)n * M_TOT + m) = o4;   // V^T[n][m]
            } else {
                bf16_t* Cp = (z == 0) ? Qw : Kw;
                #pragma unroll
                for (int r = 0; r < 4; ++r)
                    Cp[(size_t)(m + r) * N + n] = (bf16_t)((acc[i][j][r] + bvv) * scale);
            }
        }
    }
}

// ---------------------------------------------------------------------------
// Out-projection GEMM, v9: 8-phase (T3+T4) 256^2 template, grid (32,4),
// 512 threads (8 waves, 2Mx4N, 128x64/wave). LDS 128KB dbuf. Per K-tile:
// 4 phases {stage 1 half-tile (2 DMA/thr) -> counted vmcnt(2/4/6/8) ->
// barrier -> 12 ds_read_b128 -> setprio MFMA x16}; tile-closing barrier
// (next tile's stages overwrite the buffer being read). vmcnt never 0
// mid-loop: at tile t phase p, younger-than-stage(t) = 2(p+1). Granule
// swizzle g^(row&7), source-preswizzled (rule 21; r12-verified primitive).
// ---------------------------------------------------------------------------
__global__ __launch_bounds__(512, 2)
void gemm_out(const bf16_t* __restrict__ A, const bf16_t* __restrict__ Bt,
              const float* __restrict__ bias, float* __restrict__ C)
{
    constexpr int K = 1024, N = 1024;
    constexpr int BM = 256, BK = 64;
    constexpr int NT = K / BK;   // 16

    __shared__ __align__(16) bf16_t lA[2][BM * BK];   // 64 KB
    __shared__ __align__(16) bf16_t lB[2][BM * BK];   // 64 KB

    const int tid  = threadIdx.x;
    const int wave = tid >> 6;        // 0..7
    const int lane = tid & 63;

    const int row0 = blockIdx.x * BM;
    const int col0 = blockIdx.y * BM;

    const int wr = (wave >> 2) * 128; // {0,128}
    const int wc = (wave & 3) * 64;   // {0,64,128,192}

    f32x4 acc[8][4] = {};

    const int frow = lane & 15;
    const int qd   = lane >> 4;       // 0..3
    const int fr7  = frow & 7;

    // stage half-tile h of the K-tile at k0s into buffer bufi.
    // h: 0=A[0:128), 1=A[128:256), 2=B[0:128), 3=B[128:256).
    // 2 loads/thread; LDS dest linear (wave-uniform base + lane*16B);
    // global source granule pre-swizzled: gs = (lane&7) ^ (row&7).
    auto stage_half = [&](int k0s, int bufi, int h) {
        const bf16_t* G = (h < 2) ? A : Bt;
        bf16_t* L = (h < 2) ? &lA[bufi][0] : &lB[bufi][0];
        const int base0 = (h < 2) ? row0 : col0;
        const int rbase = (h & 1) * 128;
        const int gs    = ((lane & 7) ^ ((lane >> 3) & 7)) * 8;  // elem
        #pragma unroll
        for (int l = 0; l < 2; ++l) {
            const int rchunk = rbase + l * 64 + wave * 8;
            const int rloc   = rchunk + (lane >> 3);
            __builtin_amdgcn_global_load_lds(
                (gvoid*)(G + (size_t)(base0 + rloc) * K + k0s + gs),
                (lvoid*)(L + (size_t)rchunk * 64), 16, 0, 0);
        }
    };

// one phase: stage half PH of next tile, counted vmcnt, barrier, quadrant MFMA
#define GOUT_PHASE(PH, MH, NH, VCSTR)                                          \
    do {                                                                       \
        stage_half(k1, bufn, PH);                                              \
        asm volatile("s_waitcnt vmcnt(" VCSTR ")" ::: "memory");               \
        __builtin_amdgcn_s_barrier();                                          \
        bf16x8 af[4][2], bfr[2][2];                                            \
        _Pragma("unroll")                                                      \
        for (int ks = 0; ks < 2; ++ks) {                                       \
            const int kg = ((ks * 4 + qd) ^ fr7) * 8;                          \
            _Pragma("unroll")                                                  \
            for (int mf = 0; mf < 4; ++mf)                                     \
                af[mf][ks] = *(const bf16x8*)(&lA[buf][(size_t)(wr + ((MH)*4 + mf) * 16 + frow) * 64 + kg]); \
            _Pragma("unroll")                                                  \
            for (int nf = 0; nf < 2; ++nf)                                     \
                bfr[nf][ks] = *(const bf16x8*)(&lB[buf][(size_t)(wc + ((NH)*2 + nf) * 16 + frow) * 64 + kg]); \
        }                                                                      \
        __builtin_amdgcn_s_setprio(1);                                         \
        _Pragma("unroll")                                                      \
        for (int ks = 0; ks < 2; ++ks)                                         \
            _Pragma("unroll")                                                  \
            for (int mf = 0; mf < 4; ++mf)                                     \
                _Pragma("unroll")                                              \
                for (int nf = 0; nf < 2; ++nf)                                 \
                    acc[(MH)*4 + mf][(NH)*2 + nf] =                            \
                        __builtin_amdgcn_mfma_f32_16x16x32_bf16(               \
                            af[mf][ks], bfr[nf][ks],                           \
                            acc[(MH)*4 + mf][(NH)*2 + nf], 0, 0, 0);           \
        __builtin_amdgcn_s_setprio(0);                                         \
    } while (0)

#define GOUT_EPI(MH, NH)                                                       \
    do {                                                                       \
        bf16x8 af[4][2], bfr[2][2];                                            \
        _Pragma("unroll")                                                      \
        for (int ks = 0; ks < 2; ++ks) {                                       \
            const int kg = ((ks * 4 + qd) ^ fr7) * 8;                          \
            _Pragma("unroll")                                                  \
            for (int mf = 0; mf < 4; ++mf)                                     \
                af[mf][ks] = *(const bf16x8*)(&lA[buf][(size_t)(wr + ((MH)*4 + mf) * 16 + frow) * 64 + kg]); \
            _Pragma("unroll")                                                  \
            for (int nf = 0; nf < 2; ++nf)                                     \
                bfr[nf][ks] = *(const bf16x8*)(&lB[buf][(size_t)(wc + ((NH)*2 + nf) * 16 + frow) * 64 + kg]); \
        }                                                                      \
        _Pragma("unroll")                                                      \
        for (int ks = 0; ks < 2; ++ks)                                         \
            _Pragma("unroll")                                                  \
            for (int mf = 0; mf < 4; ++mf)                                     \
                _Pragma("unroll")                                              \
                for (int nf = 0; nf < 2; ++nf)                                 \
                    acc[(MH)*4 + mf][(NH)*2 + nf] =                            \
                        __builtin_amdgcn_mfma_f32_16x16x32_bf16(               \
                            af[mf][ks], bfr[nf][ks],                           \
                            acc[(MH)*4 + mf][(NH)*2 + nf], 0, 0, 0);           \
    } while (0)

    // prologue: stage all 4 half-tiles of tile 0 into buffer 0
    #pragma unroll
    for (int h = 0; h < 4; ++h) stage_half(0, 0, h);

    #pragma unroll 1
    for (int t = 0; t < NT - 1; ++t) {
        const int buf  = t & 1;
        const int bufn = buf ^ 1;
        const int k1   = (t + 1) * BK;
        GOUT_PHASE(0, 0, 0, "2");
        GOUT_PHASE(1, 0, 1, "4");
        GOUT_PHASE(2, 1, 0, "6");
        GOUT_PHASE(3, 1, 1, "8");
        // tile close: all waves' reads of buf retired (reads precede each
        // wave's MFMA issue) before next tile's stages overwrite buf.
        __builtin_amdgcn_s_barrier();
    }

    {   // last tile: no staging; drain everything once.
        const int buf = (NT - 1) & 1;
        asm volatile("s_waitcnt vmcnt(0)" ::: "memory");
        __builtin_amdgcn_s_barrier();
        GOUT_EPI(0, 0);
        GOUT_EPI(0, 1);
        GOUT_EPI(1, 0);
        GOUT_EPI(1, 1);
    }

    const int rb   = (lane >> 4) * 4;
    const int ccol = lane & 15;
    #pragma unroll
    for (int nf = 0; nf < 4; ++nf) {
        const int n = col0 + wc + nf * 16 + ccol;
        const float bvv = bias[n];
        #pragma unroll
        for (int mf = 0; mf < 8; ++mf) {
            const int m = row0 + wr + mf * 16 + rb;
            #pragma unroll
            for (int r = 0; r < 4; ++r)
                C[(size_t)(m + r) * N + n] = acc[mf][nf][r] + bvv;
        }
    }
#undef GOUT_PHASE
#undef GOUT_EPI
}

// ---------------------------------------------------------------------------
// MFMA flash attention (no max-tracking; Q pre-scaled by 0.125*log2e).
// v2: 64 q-rows per wave; T14 async-stage; T5 setprio. (verified round 2)
// ---------------------------------------------------------------------------
__global__ __launch_bounds__(256, 2)
void attn_mfma(const bf16_t* __restrict__ Qg, const bf16_t* __restrict__ Kg,
               const bf16_t* __restrict__ Vt, bf16_t* __restrict__ ctx)
{
    constexpr int PSTR = 72;
    __shared__ __align__(16) bf16_t lK[64 * PSTR];        // 9 KB
    __shared__ __align__(16) bf16_t lV[64 * PSTR];        // 9 KB
    __shared__ __align__(16) bf16_t lP[4][64 * PSTR];     // 36 KB

    const int tid  = threadIdx.x;
    const int wave = tid >> 6;
    const int lane = tid & 63;
    const int qd   = lane >> 4;
    const int c    = lane & 15;

    const int g    = blockIdx.x;           // 0..511
    const int bh   = ((g >> 6) << 3) | (g & 7);
    const int qblk = (g >> 3) & 7;
    const int b    = bh >> 4;
    const int h    = bh & 15;

    const int q0 = qblk * 256 + wave * 64;

    const bf16_t* Qb = Qg + ((size_t)(b * S_LEN + q0)) * D_DIM + h * DKD;
    const bf16_t* Kb = Kg + ((size_t)(b * S_LEN)) * D_DIM + h * DKD;
    const bf16_t* Vb = Vt + ((size_t)(h * DKD)) * M_TOT + b * S_LEN;

    bf16_t* Pw = &lP[wave][0];

    bf16x8 qf[4][2];
    #pragma unroll
    for (int qt = 0; qt < 4; ++qt)
        #pragma unroll
        for (int ks = 0; ks < 2; ++ks)
            qf[qt][ks] = *(const bf16x8*)(Qb + (size_t)(qt * 16 + c) * D_DIM + ks * 32 + qd * 8);

    bf16x8 ones;
    #pragma unroll
    for (int i = 0; i < 8; ++i) ones[i] = (bf16_t)1.0f;

    f32x4 oacc[4][4] = {};
    f32x4 lacc[4]    = {};

    const int srow = tid >> 3;
    const int sc8  = (tid & 7) * 8;

    bf16x8 kv[2], vv[2];
    #pragma unroll
    for (int cc = 0; cc < 2; ++cc) {
        const int row = cc * 32 + srow;
        kv[cc] = *(const bf16x8*)(Kb + (size_t)row * D_DIM + sc8);
        vv[cc] = *(const bf16x8*)(Vb + (size_t)row * M_TOT + sc8);
    }

    for (int kt = 0; kt < S_LEN; kt += 64) {
        __syncthreads();
        #pragma unroll
        for (int cc = 0; cc < 2; ++cc) {
            const int row = cc * 32 + srow;
            *(bf16x8*)(lK + row * PSTR + sc8) = kv[cc];
            *(bf16x8*)(lV + row * PSTR + sc8) = vv[cc];
        }
        __syncthreads();

        if (kt + 64 < S_LEN) {
            #pragma unroll
            for (int cc = 0; cc < 2; ++cc) {
                const int row = cc * 32 + srow;
                kv[cc] = *(const bf16x8*)(Kb + (size_t)(kt + 64 + row) * D_DIM + sc8);
                vv[cc] = *(const bf16x8*)(Vb + (size_t)row * M_TOT + kt + 64 + sc8);
            }
        }

        bf16x8 kf[4][2];
        #pragma unroll
        for (int i = 0; i < 4; ++i)
            #pragma unroll
            for (int ks = 0; ks < 2; ++ks)
                kf[i][ks] = *(const bf16x8*)(lK + (i * 16 + c) * PSTR + ks * 32 + qd * 8);

        #pragma unroll
        for (int qh = 0; qh < 2; ++qh) {
            f32x4 st[4][2] = {};
            __builtin_amdgcn_s_setprio(1);
            #pragma unroll
            for (int ks = 0; ks < 2; ++ks)
                #pragma unroll
                for (int i = 0; i < 4; ++i)
                    #pragma unroll
                    for (int qt = 0; qt < 2; ++qt)
                        st[i][qt] = __builtin_amdgcn_mfma_f32_16x16x32_bf16(
                            kf[i][ks], qf[qh * 2 + qt][ks], st[i][qt], 0, 0, 0);
            __builtin_amdgcn_s_setprio(0);

            #pragma unroll
            for (int i = 0; i < 4; ++i)
                #pragma unroll
                for (int qt = 0; qt < 2; ++qt) {
                    bf16x4 pw;
                    #pragma unroll
                    for (int r = 0; r < 4; ++r)
                        pw[r] = (bf16_t)__ocml_native_exp2_f32(st[i][qt][r]);
                    *(bf16x4*)(Pw + ((qh * 2 + qt) * 16 + c) * PSTR + i * 16 + qd * 4) = pw;
                }
        }

        bf16x8 vf[4][2];
        #pragma unroll
        for (int fm = 0; fm < 4; ++fm)
            #pragma unroll
            for (int ks = 0; ks < 2; ++ks)
                vf[fm][ks] = *(const bf16x8*)(lV + (fm * 16 + c) * PSTR + ks * 32 + qd * 8);

        __builtin_amdgcn_s_setprio(1);
        #pragma unroll
        for (int qn = 0; qn < 4; ++qn)
            #pragma unroll
            for (int ks = 0; ks < 2; ++ks) {
                bf16x8 pf = *(const bf16x8*)(Pw + (qn * 16 + c) * PSTR + ks * 32 + qd * 8);
                lacc[qn] = __builtin_amdgcn_mfma_f32_16x16x32_bf16(ones, pf, lacc[qn], 0, 0, 0);
                #pragma unroll
                for (int fm = 0; fm < 4; ++fm)
                    oacc[fm][qn] = __builtin_amdgcn_mfma_f32_16x16x32_bf16(vf[fm][ks], pf, oacc[fm][qn], 0, 0, 0);
            }
        __builtin_amdgcn_s_setprio(0);
    }

    #pragma unroll
    for (int qn = 0; qn < 4; ++qn) {
        const float linv = 1.0f / lacc[qn][0];
        bf16_t* op = ctx + ((size_t)(b * S_LEN + q0 + qn * 16 + c)) * D_DIM + h * DKD + qd * 4;
        #pragma unroll
        for (int fm = 0; fm < 4; ++fm) {
            bf16x4 o4;
            #pragma unroll
            for (int r = 0; r < 4; ++r) o4[r] = (bf16_t)(oacc[fm][qn][r] * linv);
            *(bf16x4*)(op + fm * 16) = o4;
        }
    }
}

// ---------------------------------------------------------------------------
extern "C" void kernel_launch(void* const* d_in, const int* in_sizes, int n_in,
                              void* d_out, int out_size, void* d_ws, size_t ws_size,
                              hipStream_t stream)
{
    const float* query = (const float*)d_in[0];
    const float* key_  = (const float*)d_in[1];
    const float* value = (const float*)d_in[2];
    const float* Wq    = (const float*)d_in[3];
    const float* bq    = (const float*)d_in[4];
    const float* Wk    = (const float*)d_in[5];
    const float* bk    = (const float*)d_in[6];
    const float* Wv    = (const float*)d_in[7];
    const float* bv    = (const float*)d_in[8];
    const float* Wo    = (const float*)d_in[9];
    const float* bo    = (const float*)d_in[10];
    float* out = (float*)d_out;

    const size_t mat  = (size_t)M_TOT * D_DIM;
    const size_t wmat = (size_t)D_DIM * D_DIM;

    // ws (bf16), 66 MB: t0 16MB (Wk'/Wv' early; ctx later) | w0 2MB (Wq'->Wo')
    //                   | Qw 16MB | Kw 16MB | Vt 16MB
    bf16_t* t0 = (bf16_t*)d_ws;
    bf16_t* w0 = t0 + mat;
    bf16_t* Qw = w0 + wmat;
    bf16_t* Kw = Qw + mat;
    bf16_t* Vt = Kw + mat;
    bf16_t* w1 = t0;                 // Wk' (dead once qkv_gemm done)
    bf16_t* w2 = t0 + wmat;          // Wv'

    const int gcvt_w = (int)(wmat / 4 / 256);
    const float qscale = 0.18033688011112042f;   // 0.125 * log2(e)

    cvt3_kernel<<<dim3(gcvt_w, 1, 3), 256, 0, stream>>>(Wq, Wk, Wv, w0, w1, w2,
                                                        (int)(wmat / 4));

    qkv_gemm<<<dim3(M_TOT / 128, D_DIM / 128, 3), 256, 0, stream>>>(
        query, key_, value, w0, w1, w2, bq, bk, bv, Qw, Kw, Vt, qscale);

    cvt_kernel<<<gcvt_w, 256, 0, stream>>>(Wo, w0, (int)(wmat / 4));  // w0 free now

    attn_mfma<<<dim3(B_SZ * NH * (S_LEN / 256)), 256, 0, stream>>>(Qw, Kw, Vt, t0);

    gemm_out<<<dim3(M_TOT / 256, D_DIM / 256), 512, 0, stream>>>(t0, w0, bo, out);
}

// Round 15
// 327.232 us; speedup vs baseline: 1.0522x; 1.0522x over previous
//
#include <hip/hip_runtime.h>
#include <hip/hip_bf16.h>
#include <math.h>

// B=4, S=2048, D=1024, H=16, DK=64. fp32 I/O. bf16 MFMA internals.

#define B_SZ   4
#define S_LEN  2048
#define D_DIM  1024
#define NH     16
#define DKD    64
#define M_TOT  (B_SZ * S_LEN)   // 8192

typedef __bf16 bf16_t;
typedef bf16_t bf16x8 __attribute__((ext_vector_type(8)));
typedef bf16_t bf16x4 __attribute__((ext_vector_type(4)));
typedef float  f32x4  __attribute__((ext_vector_type(4)));

typedef __attribute__((address_space(1))) void gvoid;
typedef __attribute__((address_space(3))) void lvoid;

extern "C" __device__ float __ocml_native_exp2_f32(float);  // single v_exp_f32

// ---------------------------------------------------------------------------
// fp32 -> bf16 convert. cvt3: three weight matrices in one launch (z selects).
// ---------------------------------------------------------------------------
__global__ __launch_bounds__(256)
void cvt3_kernel(const float* __restrict__ s0, const float* __restrict__ s1,
                 const float* __restrict__ s2, bf16_t* __restrict__ d0,
                 bf16_t* __restrict__ d1, bf16_t* __restrict__ d2, int n4)
{
    const float* src = (blockIdx.z == 0) ? s0 : (blockIdx.z == 1) ? s1 : s2;
    bf16_t*      dst = (blockIdx.z == 0) ? d0 : (blockIdx.z == 1) ? d1 : d2;
    const int i = blockIdx.x * blockDim.x + threadIdx.x;
    if (i < n4) {
        f32x4 v = *(const f32x4*)(src + (size_t)i * 4);
        bf16x4 o;
        #pragma unroll
        for (int j = 0; j < 4; ++j) o[j] = (bf16_t)v[j];
        *(bf16x4*)(dst + (size_t)i * 4) = o;
    }
}

__global__ __launch_bounds__(256)
void cvt_kernel(const float* __restrict__ src, bf16_t* __restrict__ dst, int n4)
{
    const int i = blockIdx.x * blockDim.x + threadIdx.x;
    if (i < n4) {
        f32x4 v = *(const f32x4*)(src + (size_t)i * 4);
        bf16x4 o;
        #pragma unroll
        for (int j = 0; j < 4; ++j) o[j] = (bf16_t)v[j];
        *(bf16x4*)(dst + (size_t)i * 4) = o;
    }
}

// ---------------------------------------------------------------------------
// Fused QKV projection GEMM, grid (64, 8, 3). r5-measured-best body (~107us):
// BM=BN=128, B double-buffered gload_lds with counted vmcnt, A reg-staged.
// No XCD remap (r11 showed remap costs qkv +11us).
// ---------------------------------------------------------------------------
__global__ __launch_bounds__(256, 3)
void qkv_gemm(const float* __restrict__ Aq, const float* __restrict__ Ak,
              const float* __restrict__ Av,
              const bf16_t* __restrict__ Wqb, const bf16_t* __restrict__ Wkb,
              const bf16_t* __restrict__ Wvb,
              const float* __restrict__ bq, const float* __restrict__ bk,
              const float* __restrict__ bv,
              bf16_t* __restrict__ Qw, bf16_t* __restrict__ Kw,
              bf16_t* __restrict__ Vt, float qscale)
{
    constexpr int K = 1024, N = 1024;
    constexpr int BM = 128, BK = 64;
    constexpr int NT = K / BK;     // 16 K-steps

    __shared__ __align__(16) bf16_t lA[2][BM * 32];      // [sub]      16 KB
    __shared__ __align__(16) bf16_t lB[2][2][128 * 32];  // [buf][sub] 32 KB

    const int z = blockIdx.z;
    const float* A  = (z == 0) ? Aq : (z == 1) ? Ak : Av;
    const bf16_t* W = (z == 0) ? Wqb : (z == 1) ? Wkb : Wvb;
    const float* bias = (z == 0) ? bq : (z == 1) ? bk : bv;
    const float scale = (z == 0) ? qscale : 1.0f;

    const int tid  = threadIdx.x;
    const int wave = tid >> 6;
    const int lane = tid & 63;

    const int row0 = blockIdx.x * BM;
    const int col0 = blockIdx.y * 128;

    const int wr = (wave >> 1) * 64;
    const int wc = (wave & 1) * 64;

    f32x4 acc[4][4] = {};

    const int frow = lane & 15;
    const int kq   = (lane >> 4) * 8;

    const int arow = tid >> 3;          // + p*32
    const int ak8  = (tid & 7) * 8;     // k offset in tile
    const int asub = (tid >> 2) & 1;
    const int akk  = (tid & 3) * 8;

    auto stageB = [&](int k0s, int bufi) {
        #pragma unroll
        for (int s = 0; s < 2; ++s)
            #pragma unroll
            for (int c2 = 0; c2 < 2; ++c2) {
                const int chunk = c2 * 4 + wave;
                const int e     = chunk * 512 + lane * 8;
                const int rr    = e >> 5;
                const int kk    = e & 31;
                __builtin_amdgcn_global_load_lds(
                    (gvoid*)(W + (size_t)(col0 + rr) * K + k0s + 32 * s + kk),
                    (lvoid*)(&lB[bufi][s][chunk * 512]), 16, 0, 0);
            }
    };

    stageB(0, 0);

    f32x4 pa[4][2];
    #pragma unroll
    for (int p = 0; p < 4; ++p) {
        const float* g = A + (size_t)(row0 + p * 32 + arow) * K + ak8;
        pa[p][0] = *(const f32x4*)g;
        pa[p][1] = *(const f32x4*)(g + 4);
    }

    for (int t = 0; t < NT; ++t) {
        const int k0  = t * BK;
        const int buf = t & 1;

        if (t + 1 < NT) stageB(k0 + BK, buf ^ 1);

        #pragma unroll
        for (int p = 0; p < 4; ++p) {
            bf16x8 a8;
            #pragma unroll
            for (int j = 0; j < 4; ++j) {
                a8[j]     = (bf16_t)pa[p][0][j];
                a8[4 + j] = (bf16_t)pa[p][1][j];
            }
            *(bf16x8*)(&lA[asub][(p * 32 + arow) * 32 + akk]) = a8;
        }

        if (t + 1 < NT)
            asm volatile("s_waitcnt vmcnt(4) lgkmcnt(0)" ::: "memory");
        else
            asm volatile("s_waitcnt vmcnt(0) lgkmcnt(0)" ::: "memory");
        __builtin_amdgcn_s_barrier();

        if (t + 1 < NT) {
            #pragma unroll
            for (int p = 0; p < 4; ++p) {
                const float* g = A + (size_t)(row0 + p * 32 + arow) * K + (k0 + BK) + ak8;
                pa[p][0] = *(const f32x4*)g;
                pa[p][1] = *(const f32x4*)(g + 4);
            }
        }

        #pragma unroll
        for (int s = 0; s < 2; ++s) {
            bf16x8 af[4], bfr[4];
            #pragma unroll
            for (int i = 0; i < 4; ++i) {
                af[i]  = *(const bf16x8*)(&lA[s][(wr + i * 16 + frow) * 32 + kq]);
                bfr[i] = *(const bf16x8*)(&lB[buf][s][(wc + i * 16 + frow) * 32 + kq]);
            }
            #pragma unroll
            for (int i = 0; i < 4; ++i)
                #pragma unroll
                for (int j = 0; j < 4; ++j)
                    acc[i][j] = __builtin_amdgcn_mfma_f32_16x16x32_bf16(af[i], bfr[j], acc[i][j], 0, 0, 0);
        }

        asm volatile("" ::: "memory");
        __builtin_amdgcn_s_barrier();
    }

    // C/D layout: col=lane&15, row=(lane>>4)*4+reg  [m89/m91-verified]
    const int rb   = (lane >> 4) * 4;
    const int ccol = lane & 15;
    #pragma unroll
    for (int j = 0; j < 4; ++j) {
        const int n = col0 + wc + j * 16 + ccol;
        const float bvv = bias[n];
        #pragma unroll
        for (int i = 0; i < 4; ++i) {
            const int m = row0 + wr + i * 16 + rb;
            if (z == 2) {
                bf16x4 o4;
                #pragma unroll
                for (int r = 0; r < 4; ++r) o4[r] = (bf16_t)(acc[i][j][r] + bvv);
                *(bf16x4*)(Vt + (size_t)n * M_TOT + m) = o4;   // V^T[n][m]
            } else {
                bf16_t* Cp = (z == 0) ? Qw : Kw;
                #pragma unroll
                for (int r = 0; r < 4; ++r)
                    Cp[(size_t)(m + r) * N + n] = (bf16_t)((acc[i][j][r] + bvv) * scale);
            }
        }
    }
}

// ---------------------------------------------------------------------------
// Out-projection GEMM, 1-D grid 512. r5 2-phase dbuf body + r11's
// XCD-colocation remap (the only positive gemm_out signal: best-total round
// r11 had this; Wo stays L2-resident per XCD, the 8 y-blocks of each x are
// XCD-colocated). bid = c + 8*(y + 8*xhi), x = xhi*8 + c. LDS 64KB, 2 blk/CU.
// ---------------------------------------------------------------------------
__global__ __launch_bounds__(256, 2)
void gemm_out(const bf16_t* __restrict__ A, const bf16_t* __restrict__ Bt,
              const float* __restrict__ bias, float* __restrict__ C)
{
    constexpr int K = 1024, N = 1024;
    constexpr int BM = 128, BK = 64;
    constexpr int NT = K / BK;

    __shared__ __align__(16) bf16_t lA[2][2][BM * 32];   // [buf][sub] 32 KB
    __shared__ __align__(16) bf16_t lB[2][2][128 * 32];  // 32 KB

    // XCD-colocation decode
    const int bid = blockIdx.x;
    const int c   = bid & 7;
    const int r1  = bid >> 3;
    const int by  = r1 & 7;
    const int bx  = (r1 >> 3) * 8 + c;

    const int tid  = threadIdx.x;
    const int wave = tid >> 6;
    const int lane = tid & 63;

    const int row0 = bx * BM;
    const int col0 = by * 128;

    const int wr = (wave >> 1) * 64;
    const int wc = (wave & 1) * 64;

    f32x4 acc[4][4] = {};

    const int frow = lane & 15;
    const int kq   = (lane >> 4) * 8;

    auto stage = [&](int k0s, int bufi) {
        #pragma unroll
        for (int s = 0; s < 2; ++s)
            #pragma unroll
            for (int c2 = 0; c2 < 2; ++c2) {
                const int chunk = c2 * 4 + wave;
                const int e     = chunk * 512 + lane * 8;
                const int r     = e >> 5;
                const int kk    = e & 31;
                __builtin_amdgcn_global_load_lds(
                    (gvoid*)(A + (size_t)(row0 + r) * K + k0s + 32 * s + kk),
                    (lvoid*)(&lA[bufi][s][chunk * 512]), 16, 0, 0);
                __builtin_amdgcn_global_load_lds(
                    (gvoid*)(Bt + (size_t)(col0 + r) * K + k0s + 32 * s + kk),
                    (lvoid*)(&lB[bufi][s][chunk * 512]), 16, 0, 0);
            }
    };

    stage(0, 0);   // prologue

    for (int t = 0; t < NT; ++t) {
        const int buf = t & 1;

        if (t + 1 < NT) {
            stage((t + 1) * BK, buf ^ 1);
            asm volatile("s_waitcnt vmcnt(8)" ::: "memory");
        } else {
            asm volatile("s_waitcnt vmcnt(0)" ::: "memory");
        }
        __builtin_amdgcn_s_barrier();

        #pragma unroll
        for (int s = 0; s < 2; ++s) {
            bf16x8 af[4], bfr[4];
            #pragma unroll
            for (int i = 0; i < 4; ++i) {
                af[i]  = *(const bf16x8*)(&lA[buf][s][(wr + i * 16 + frow) * 32 + kq]);
                bfr[i] = *(const bf16x8*)(&lB[buf][s][(wc + i * 16 + frow) * 32 + kq]);
            }
            #pragma unroll
            for (int i = 0; i < 4; ++i)
                #pragma unroll
                for (int j = 0; j < 4; ++j)
                    acc[i][j] = __builtin_amdgcn_mfma_f32_16x16x32_bf16(af[i], bfr[j], acc[i][j], 0, 0, 0);
        }

        asm volatile("" ::: "memory");
        __builtin_amdgcn_s_barrier();
    }

    const int rb   = (lane >> 4) * 4;
    const int ccol = lane & 15;
    #pragma unroll
    for (int j = 0; j < 4; ++j) {
        const int n = col0 + wc + j * 16 + ccol;
        const float bvv = bias[n];
        #pragma unroll
        for (int i = 0; i < 4; ++i) {
            const int m = row0 + wr + i * 16 + rb;
            #pragma unroll
            for (int r = 0; r < 4; ++r)
                C[(size_t)(m + r) * N + n] = acc[i][j][r] + bvv;
        }
    }
}

// ---------------------------------------------------------------------------
// MFMA flash attention (no max-tracking; Q pre-scaled by 0.125*log2e).
// v2: 64 q-rows per wave; T14 async-stage; T5 setprio. (verified round 2)
// ---------------------------------------------------------------------------
__global__ __launch_bounds__(256, 2)
void attn_mfma(const bf16_t* __restrict__ Qg, const bf16_t* __restrict__ Kg,
               const bf16_t* __restrict__ Vt, bf16_t* __restrict__ ctx)
{
    constexpr int PSTR = 72;
    __shared__ __align__(16) bf16_t lK[64 * PSTR];        // 9 KB
    __shared__ __align__(16) bf16_t lV[64 * PSTR];        // 9 KB
    __shared__ __align__(16) bf16_t lP[4][64 * PSTR];     // 36 KB

    const int tid  = threadIdx.x;
    const int wave = tid >> 6;
    const int lane = tid & 63;
    const int qd   = lane >> 4;
    const int c    = lane & 15;

    const int g    = blockIdx.x;           // 0..511
    const int bh   = ((g >> 6) << 3) | (g & 7);
    const int qblk = (g >> 3) & 7;
    const int b    = bh >> 4;
    const int h    = bh & 15;

    const int q0 = qblk * 256 + wave * 64;

    const bf16_t* Qb = Qg + ((size_t)(b * S_LEN + q0)) * D_DIM + h * DKD;
    const bf16_t* Kb = Kg + ((size_t)(b * S_LEN)) * D_DIM + h * DKD;
    const bf16_t* Vb = Vt + ((size_t)(h * DKD)) * M_TOT + b * S_LEN;

    bf16_t* Pw = &lP[wave][0];

    bf16x8 qf[4][2];
    #pragma unroll
    for (int qt = 0; qt < 4; ++qt)
        #pragma unroll
        for (int ks = 0; ks < 2; ++ks)
            qf[qt][ks] = *(const bf16x8*)(Qb + (size_t)(qt * 16 + c) * D_DIM + ks * 32 + qd * 8);

    bf16x8 ones;
    #pragma unroll
    for (int i = 0; i < 8; ++i) ones[i] = (bf16_t)1.0f;

    f32x4 oacc[4][4] = {};
    f32x4 lacc[4]    = {};

    const int srow = tid >> 3;
    const int sc8  = (tid & 7) * 8;

    bf16x8 kv[2], vv[2];
    #pragma unroll
    for (int cc = 0; cc < 2; ++cc) {
        const int row = cc * 32 + srow;
        kv[cc] = *(const bf16x8*)(Kb + (size_t)row * D_DIM + sc8);
        vv[cc] = *(const bf16x8*)(Vb + (size_t)row * M_TOT + sc8);
    }

    for (int kt = 0; kt < S_LEN; kt += 64) {
        __syncthreads();
        #pragma unroll
        for (int cc = 0; cc < 2; ++cc) {
            const int row = cc * 32 + srow;
            *(bf16x8*)(lK + row * PSTR + sc8) = kv[cc];
            *(bf16x8*)(lV + row * PSTR + sc8) = vv[cc];
        }
        __syncthreads();

        if (kt + 64 < S_LEN) {
            #pragma unroll
            for (int cc = 0; cc < 2; ++cc) {
                const int row = cc * 32 + srow;
                kv[cc] = *(const bf16x8*)(Kb + (size_t)(kt + 64 + row) * D_DIM + sc8);
                vv[cc] = *(const bf16x8*)(Vb + (size_t)row * M_TOT + kt + 64 + sc8);
            }
        }

        bf16x8 kf[4][2];
        #pragma unroll
        for (int i = 0; i < 4; ++i)
            #pragma unroll
            for (int ks = 0; ks < 2; ++ks)
                kf[i][ks] = *(const bf16x8*)(lK + (i * 16 + c) * PSTR + ks * 32 + qd * 8);

        #pragma unroll
        for (int qh = 0; qh < 2; ++qh) {
            f32x4 st[4][2] = {};
            __builtin_amdgcn_s_setprio(1);
            #pragma unroll
            for (int ks = 0; ks < 2; ++ks)
                #pragma unroll
                for (int i = 0; i < 4; ++i)
                    #pragma unroll
                    for (int qt = 0; qt < 2; ++qt)
                        st[i][qt] = __builtin_amdgcn_mfma_f32_16x16x32_bf16(
                            kf[i][ks], qf[qh * 2 + qt][ks], st[i][qt], 0, 0, 0);
            __builtin_amdgcn_s_setprio(0);

            #pragma unroll
            for (int i = 0; i < 4; ++i)
                #pragma unroll
                for (int qt = 0; qt < 2; ++qt) {
                    bf16x4 pw;
                    #pragma unroll
                    for (int r = 0; r < 4; ++r)
                        pw[r] = (bf16_t)__ocml_native_exp2_f32(st[i][qt][r]);
                    *(bf16x4*)(Pw + ((qh * 2 + qt) * 16 + c) * PSTR + i * 16 + qd * 4) = pw;
                }
        }

        bf16x8 vf[4][2];
        #pragma unroll
        for (int fm = 0; fm < 4; ++fm)
            #pragma unroll
            for (int ks = 0; ks < 2; ++ks)
                vf[fm][ks] = *(const bf16x8*)(lV + (fm * 16 + c) * PSTR + ks * 32 + qd * 8);

        __builtin_amdgcn_s_setprio(1);
        #pragma unroll
        for (int qn = 0; qn < 4; ++qn)
            #pragma unroll
            for (int ks = 0; ks < 2; ++ks) {
                bf16x8 pf = *(const bf16x8*)(Pw + (qn * 16 + c) * PSTR + ks * 32 + qd * 8);
                lacc[qn] = __builtin_amdgcn_mfma_f32_16x16x32_bf16(ones, pf, lacc[qn], 0, 0, 0);
                #pragma unroll
                for (int fm = 0; fm < 4; ++fm)
                    oacc[fm][qn] = __builtin_amdgcn_mfma_f32_16x16x32_bf16(vf[fm][ks], pf, oacc[fm][qn], 0, 0, 0);
            }
        __builtin_amdgcn_s_setprio(0);
    }

    #pragma unroll
    for (int qn = 0; qn < 4; ++qn) {
        const float linv = 1.0f / lacc[qn][0];
        bf16_t* op = ctx + ((size_t)(b * S_LEN + q0 + qn * 16 + c)) * D_DIM + h * DKD + qd * 4;
        #pragma unroll
        for (int fm = 0; fm < 4; ++fm) {
            bf16x4 o4;
            #pragma unroll
            for (int r = 0; r < 4; ++r) o4[r] = (bf16_t)(oacc[fm][qn][r] * linv);
            *(bf16x4*)(op + fm * 16) = o4;
        }
    }
}

// ---------------------------------------------------------------------------
extern "C" void kernel_launch(void* const* d_in, const int* in_sizes, int n_in,
                              void* d_out, int out_size, void* d_ws, size_t ws_size,
                              hipStream_t stream)
{
    const float* query = (const float*)d_in[0];
    const float* key_  = (const float*)d_in[1];
    const float* value = (const float*)d_in[2];
    const float* Wq    = (const float*)d_in[3];
    const float* bq    = (const float*)d_in[4];
    const float* Wk    = (const float*)d_in[5];
    const float* bk    = (const float*)d_in[6];
    const float* Wv    = (const float*)d_in[7];
    const float* bv    = (const float*)d_in[8];
    const float* Wo    = (const float*)d_in[9];
    const float* bo    = (const float*)d_in[10];
    float* out = (float*)d_out;

    const size_t mat  = (size_t)M_TOT * D_DIM;
    const size_t wmat = (size_t)D_DIM * D_DIM;

    // ws (bf16), 66 MB: t0 16MB (Wk'/Wv' early; ctx later) | w0 2MB (Wq'->Wo')
    //                   | Qw 16MB | Kw 16MB | Vt 16MB
    bf16_t* t0 = (bf16_t*)d_ws;
    bf16_t* w0 = t0 + mat;
    bf16_t* Qw = w0 + wmat;
    bf16_t* Kw = Qw + mat;
    bf16_t* Vt = Kw + mat;
    bf16_t* w1 = t0;                 // Wk' (dead once qkv_gemm done)
    bf16_t* w2 = t0 + wmat;          // Wv'

    const int gcvt_w = (int)(wmat / 4 / 256);
    const float qscale = 0.18033688011112042f;   // 0.125 * log2(e)

    cvt3_kernel<<<dim3(gcvt_w, 1, 3), 256, 0, stream>>>(Wq, Wk, Wv, w0, w1, w2,
                                                        (int)(wmat / 4));

    qkv_gemm<<<dim3(M_TOT / 128, D_DIM / 128, 3), 256, 0, stream>>>(
        query, key_, value, w0, w1, w2, bq, bk, bv, Qw, Kw, Vt, qscale);

    cvt_kernel<<<gcvt_w, 256, 0, stream>>>(Wo, w0, (int)(wmat / 4));  // w0 free now

    attn_mfma<<<dim3(B_SZ * NH * (S_LEN / 256)), 256, 0, stream>>>(Qw, Kw, Vt, t0);

    gemm_out<<<dim3(512), 256, 0, stream>>>(t0, w0, bo, out);
}